// Round 6
// baseline (1566.432 us; speedup 1.0000x reference)
//
#include <hip/hip_runtime.h>
#include <hip/hip_bf16.h>
#include <hip/hip_cooperative_groups.h>

namespace cg = cooperative_groups;

typedef __attribute__((ext_vector_type(4))) float f32x4;
typedef __attribute__((ext_vector_type(8))) short s16x8;

// problem constants (fixed instance)
#define SEQ   64
#define EMB   256
#define HID   512
#define NROW  1024          // sentences
#define NTHR  512
#define NGRID 256
#define LDS_BYTES 98304     // 24 kc * 4 gates * 64 lanes * 16B, fragment-order W

// workspace layout (bytes) — identical to the R1/R4/R5 (passing) layout
#define XB_OFF   0ull                                   // bf16 x: [65536][256]
#define WHH_OFF  (XB_OFF + 65536ull * EMB * 2)          // bf16 [2][2048][512]
#define WIH_OFF  (WHH_OFF + 2ull * 2048 * HID * 2)      // bf16 [2][2048][256]
#define HB_OFF   (WIH_OFF + 2ull * 2048 * EMB * 2)      // bf16 [2 parity][2 dir][1024][512]
#define SL_OFF   (HB_OFF + 4ull * NROW * HID * 2)       // int [1024]
#define BAR_OFF  (SL_OFF + 4096ull)                     // unsigned [8]

__device__ __forceinline__ unsigned short f2bf(float f) {
    union { float f; unsigned u; } x; x.f = f;
    unsigned r = x.u + 0x7fffu + ((x.u >> 16) & 1u);   // RNE
    return (unsigned short)(r >> 16);
}
__device__ __forceinline__ void cvt8(unsigned short* dst, const float* src) {
    f32x4 v0 = *(const f32x4*)src;
    f32x4 v1 = *(const f32x4*)(src + 4);
    s16x8 o;
    o[0] = (short)f2bf(v0[0]); o[1] = (short)f2bf(v0[1]);
    o[2] = (short)f2bf(v0[2]); o[3] = (short)f2bf(v0[3]);
    o[4] = (short)f2bf(v1[0]); o[5] = (short)f2bf(v1[1]);
    o[6] = (short)f2bf(v1[2]); o[7] = (short)f2bf(v1[3]);
    *(s16x8*)dst = o;
}
__device__ __forceinline__ float sigf(float x)  { return 1.0f / (1.0f + __expf(-x)); }
__device__ __forceinline__ float tanh_(float x) { return 2.0f / (1.0f + __expf(-2.0f * x)) - 1.0f; }

__global__ void __launch_bounds__(NTHR, 2)
lstm_enc(const int* __restrict__ docs, const int* __restrict__ doc_lens,
         const float* __restrict__ embed,
         const float* __restrict__ w_ih_f, const float* __restrict__ w_hh_f, const float* __restrict__ b_f,
         const float* __restrict__ w_ih_b, const float* __restrict__ w_hh_b, const float* __restrict__ b_b,
         float* __restrict__ out, unsigned char* __restrict__ ws)
{
    extern __shared__ unsigned short Wf[];   // [24 kc][4 g][64 lane][8] bf16, MFMA B-frag order

    unsigned short* xb  = (unsigned short*)(ws + XB_OFF);
    unsigned short* whh = (unsigned short*)(ws + WHH_OFF);
    unsigned short* wih = (unsigned short*)(ws + WIH_OFF);
    unsigned short* hb  = (unsigned short*)(ws + HB_OFF);
    int*       sl  = (int*)(ws + SL_OFF);
    unsigned*  bar = (unsigned*)(ws + BAR_OFF);

    const int tid = threadIdx.x;
    const int bid = blockIdx.x;
    const int gid = bid * NTHR + tid;        // 0..131071

    // ---------------- phase 0: convert / gather / init (verbatim R5) ----------------
    for (int i = 0; i < 16; ++i) {
        int slot = gid + i * (NGRID * NTHR);
        int row = slot >> 5;                // sentence*64 + t
        int e   = (slot & 31) << 3;
        int tok = docs[row];
        cvt8(xb + (size_t)slot * 8, embed + (size_t)tok * EMB + e);
    }
    cvt8(whh + (size_t)gid * 8,             w_hh_f + (size_t)gid * 8);
    cvt8(whh + (size_t)(gid + 131072) * 8,  w_hh_b + (size_t)gid * 8);
    {
        int dir0 = gid >> 16;
        int idx  = gid & 65535;
        cvt8(wih + (size_t)gid * 8, (dir0 ? w_ih_b : w_ih_f) + (size_t)idx * 8);
    }
    {
        s16x8 z = {0,0,0,0,0,0,0,0};
        *(s16x8*)(hb + (size_t)gid * 8) = z;   // parity-0, both dirs (made visible by grid.sync)
    }
    if (gid < NROW) {
        int c = 0;
        const int* dr = docs + gid * SEQ;
        for (int s2 = 0; s2 < SEQ; ++s2) c += (dr[s2] != 0);
        sl[gid] = c;
    }
    if (gid < 8) bar[gid] = 0u;

    cg::this_grid().sync();

    // ---------------- decode block role (verbatim R5) ----------------
    const int grp = bid & 7;         // barrier group: 32 WGs each (same dir,rg); XCD-local heuristic
    const int dir = grp >> 2;        // 0 fwd, 1 bwd
    const int rg  = grp & 3;         // row group (256 rows)
    const int cgd = bid >> 3;        // 0..31 : hidden-unit chunk of 16
    const int rowbase = rg * 256;
    const int hubase  = cgd * 16;

    // ---------------- W -> LDS, FRAGMENT order (verbatim R5) ----------------
    {
        const unsigned short* whh_d = whh + (size_t)dir * 2048 * HID;
        const unsigned short* wih_d = wih + (size_t)dir * 2048 * EMB;
        for (int s2 = 0; s2 < 12; ++s2) {
            int S = s2 * NTHR + tid;        // 0..6143 oct-slots = [24 kc][4 g][64 lane]
            int f = S >> 6, lane_s = S & 63;
            int kc = f >> 2, g = f & 3;
            int l15s = lane_s & 15, lqs = lane_s >> 4;
            int gn = g * HID + hubase + l15s;
            int k  = kc * 32 + lqs * 8;
            const unsigned short* src = (k < HID)
                ? (whh_d + (size_t)gn * HID + k)
                : (wih_d + (size_t)gn * EMB + (k - HID));
            *(s16x8*)(Wf + (size_t)S * 8) = *(const s16x8*)src;
        }
    }
    __syncthreads();

    // ---------------- per-lane setup (verbatim R5) ----------------
    const int wid = tid >> 6, lane = tid & 63, l15 = lane & 15, lq = lane >> 4;
    const int hu = hubase + l15;
    const float* bsrc = dir ? b_b : b_f;
    const float bi_ = bsrc[hu], bf_ = bsrc[HID + hu], bg_ = bsrc[2 * HID + hu], bo_ = bsrc[3 * HID + hu];

    int rA[2];
    rA[0] = rowbase + wid * 32 + l15;
    rA[1] = rowbase + wid * 32 + 16 + l15;

    int gr8[8]; int sl8[8]; float c8[8], pool8[8];
    #pragma unroll
    for (int rf = 0; rf < 2; ++rf)
        #pragma unroll
        for (int r = 0; r < 4; ++r) {
            int k8 = rf * 4 + r;
            gr8[k8] = rowbase + wid * 32 + rf * 16 + lq * 4 + r;
            sl8[k8] = sl[gr8[k8]];
            c8[k8] = 0.f; pool8[k8] = 0.f;
        }

    // ---------------- recurrence ----------------
    #pragma unroll 1
    for (int t = 0; t < SEQ; ++t) {
        const int te = dir ? (SEQ - 1 - t) : t;
        const unsigned short* hrd = hb + (size_t)((t & 1) * 2 + dir) * NROW * HID;
        unsigned short* hwr       = hb + (size_t)((((t + 1) & 1)) * 2 + dir) * NROW * HID;

        f32x4 acc[2][4];
        #pragma unroll
        for (int rf = 0; rf < 2; ++rf)
            #pragma unroll
            for (int g = 0; g < 4; ++g)
                acc[rf][g] = (f32x4){0.f, 0.f, 0.f, 0.f};

        // A-chunk loads: h (kc<16) via device-scope relaxed atomic 8B loads — read the
        // coherence point directly, correct for any WG->XCD placement, NO L2 invalidate
        // needed anywhere. x (kc>=16) stays a plain cached load (x is immutable; its L2
        // lines now stay warm across all 64 steps).
        auto ldA = [&](s16x8* dst, int kc) {
            #pragma unroll
            for (int rf = 0; rf < 2; ++rf) {
                if (kc < 16) {
                    const unsigned long long* p = (const unsigned long long*)
                        (hrd + (size_t)rA[rf] * HID + kc * 32 + lq * 8);
                    union { unsigned long long q[2]; s16x8 v; } u;
                    u.q[0] = __hip_atomic_load(p,     __ATOMIC_RELAXED, __HIP_MEMORY_SCOPE_AGENT);
                    u.q[1] = __hip_atomic_load(p + 1, __ATOMIC_RELAXED, __HIP_MEMORY_SCOPE_AGENT);
                    dst[rf] = u.v;
                } else {
                    const unsigned short* p =
                        xb + ((size_t)rA[rf] * SEQ + te) * EMB + (kc - 16) * 32 + lq * 8;
                    dst[rf] = *(const s16x8*)p;
                }
            }
        };

        s16x8 Abuf[2][2];   // [parity][rf]; prefetch distance 1 => write buf != read buf, no WAR hazard
        ldA(Abuf[0], 0);
        #pragma unroll
        for (int kc = 0; kc < 24; ++kc) {
            if (kc < 23) ldA(Abuf[(kc + 1) & 1], kc + 1);
            s16x8 Bf[4];
            #pragma unroll
            for (int g = 0; g < 4; ++g)
                Bf[g] = *(const s16x8*)(Wf + ((size_t)(kc * 4 + g) * 64 + lane) * 8);
            #pragma unroll
            for (int rf = 0; rf < 2; ++rf)
                #pragma unroll
                for (int g = 0; g < 4; ++g)
                    acc[rf][g] = __builtin_amdgcn_mfma_f32_16x16x32_bf16(
                        Abuf[kc & 1][rf], Bf[g], acc[rf][g], 0, 0, 0);
        }

        // elementwise LSTM update; h stores are device-scope write-through atomics:
        // globally visible once vmcnt retires (the __syncthreads below drains vmcnt).
        #pragma unroll
        for (int rf = 0; rf < 2; ++rf) {
            #pragma unroll
            for (int r = 0; r < 4; ++r) {
                int k8 = rf * 4 + r;
                float iv = acc[rf][0][r] + bi_;
                float fv = acc[rf][1][r] + bf_;
                float gv = acc[rf][2][r] + bg_;
                float ov = acc[rf][3][r] + bo_;
                float cc = sigf(fv) * c8[k8] + sigf(iv) * tanh_(gv);
                c8[k8] = cc;
                float hh = sigf(ov) * tanh_(cc);
                __hip_atomic_store(hwr + (size_t)gr8[k8] * HID + hu, f2bf(hh),
                                   __ATOMIC_RELAXED, __HIP_MEMORY_SCOPE_AGENT);
                if (te < sl8[k8]) pool8[k8] += hh;
            }
        }

        // 32-WG group barrier. All h stores are at the coherence point before tid0's
        // increment (vmcnt(0) from __syncthreads). Consumers read h via device-scope
        // atomic loads, so NO acquire/invalidate is needed — L2 stays warm for x/W.
        __syncthreads();
        if (tid == 0) {
            __hip_atomic_fetch_add(bar + grp, 1u, __ATOMIC_RELAXED, __HIP_MEMORY_SCOPE_AGENT);
            unsigned tgt = 32u * (unsigned)(t + 1);
            while (__hip_atomic_load(bar + grp, __ATOMIC_RELAXED, __HIP_MEMORY_SCOPE_AGENT) < tgt)
                __builtin_amdgcn_s_sleep(1);
        }
        __syncthreads();
    }

    // ---------------- pooled output (verbatim R5) ----------------
    #pragma unroll
    for (int k8 = 0; k8 < 8; ++k8) {
        int gr = gr8[k8];
        int b = gr >> 5, d = gr & 31;
        float denom = (float)(sl8[k8] > 0 ? sl8[k8] : 1);
        float v = (d < doc_lens[b]) ? (pool8[k8] / denom) : 0.f;
        out[(size_t)gr * 1024 + (size_t)dir * HID + hu] = v;
    }
}

extern "C" void kernel_launch(void* const* d_in, const int* in_sizes, int n_in,
                              void* d_out, int out_size, void* d_ws, size_t ws_size,
                              hipStream_t stream) {
    const int*   docs     = (const int*)d_in[0];
    const int*   doc_lens = (const int*)d_in[1];
    /* d_in[2] = max_doc_len scalar (unused; fixed 32) */
    const float* embed    = (const float*)d_in[3];
    const float* w_ih_f   = (const float*)d_in[4];
    const float* w_hh_f   = (const float*)d_in[5];
    const float* b_f      = (const float*)d_in[6];
    const float* w_ih_b   = (const float*)d_in[7];
    const float* w_hh_b   = (const float*)d_in[8];
    const float* b_b      = (const float*)d_in[9];
    float* out = (float*)d_out;
    unsigned char* wsp = (unsigned char*)d_ws;

    (void)in_sizes; (void)n_in; (void)out_size; (void)ws_size;

    hipFuncSetAttribute((const void*)lstm_enc,
                        hipFuncAttributeMaxDynamicSharedMemorySize, LDS_BYTES);

    void* args[] = { &docs, &doc_lens, &embed, &w_ih_f, &w_hh_f, &b_f,
                     &w_ih_b, &w_hh_b, &b_b, &out, &wsp };
    hipLaunchCooperativeKernel((void*)lstm_enc, dim3(NGRID), dim3(NTHR),
                               args, (unsigned)LDS_BYTES, stream);
}

// Round 7
// 1090.367 us; speedup vs baseline: 1.4366x; 1.4366x over previous
//
#include <hip/hip_runtime.h>
#include <hip/hip_bf16.h>
#include <hip/hip_cooperative_groups.h>

namespace cg = cooperative_groups;

typedef __attribute__((ext_vector_type(4))) float f32x4;
typedef __attribute__((ext_vector_type(8))) short s16x8;

// problem constants (fixed instance)
#define SEQ   64
#define EMB   256
#define HID   512
#define NROW  1024          // sentences
#define NTHR  512
#define NGRID 256
#define LDS_BYTES 98304     // 24 kc * 4 gates * 64 lanes * 16B, fragment-order W

// workspace layout (bytes)
#define XB_OFF   0ull                                   // bf16 x: [65536][256]
#define WHH_OFF  (XB_OFF + 65536ull * EMB * 2)          // bf16 [2][2048][512]
#define WIH_OFF  (WHH_OFF + 2ull * 2048 * HID * 2)      // bf16 [2][2048][256]
#define HB_OFF   (WIH_OFF + 2ull * 2048 * EMB * 2)      // bf16 [2 parity][2 dir][1024][512]
#define SL_OFF   (HB_OFF + 4ull * NROW * HID * 2)       // int [1024]
#define BAR_OFF  (SL_OFF + 4096ull)                     // unsigned [8]
#define XCDW_OFF (BAR_OFF + 64ull)                      // unsigned [256] : per-WG XCC id

__device__ __forceinline__ unsigned short f2bf(float f) {
    union { float f; unsigned u; } x; x.f = f;
    unsigned r = x.u + 0x7fffu + ((x.u >> 16) & 1u);   // RNE
    return (unsigned short)(r >> 16);
}
__device__ __forceinline__ void cvt8(unsigned short* dst, const float* src) {
    f32x4 v0 = *(const f32x4*)src;
    f32x4 v1 = *(const f32x4*)(src + 4);
    s16x8 o;
    o[0] = (short)f2bf(v0[0]); o[1] = (short)f2bf(v0[1]);
    o[2] = (short)f2bf(v0[2]); o[3] = (short)f2bf(v0[3]);
    o[4] = (short)f2bf(v1[0]); o[5] = (short)f2bf(v1[1]);
    o[6] = (short)f2bf(v1[2]); o[7] = (short)f2bf(v1[3]);
    *(s16x8*)dst = o;
}
__device__ __forceinline__ float sigf(float x)  { return 1.0f / (1.0f + __expf(-x)); }
__device__ __forceinline__ float tanh_(float x) { return 2.0f / (1.0f + __expf(-2.0f * x)) - 1.0f; }

__global__ void __launch_bounds__(NTHR, 2)
lstm_enc(const int* __restrict__ docs, const int* __restrict__ doc_lens,
         const float* __restrict__ embed,
         const float* __restrict__ w_ih_f, const float* __restrict__ w_hh_f, const float* __restrict__ b_f,
         const float* __restrict__ w_ih_b, const float* __restrict__ w_hh_b, const float* __restrict__ b_b,
         float* __restrict__ out, unsigned char* __restrict__ ws)
{
    extern __shared__ unsigned short Wf[];   // [24 kc][4 g][64 lane][8] bf16, MFMA B-frag order

    unsigned short* xb  = (unsigned short*)(ws + XB_OFF);
    unsigned short* whh = (unsigned short*)(ws + WHH_OFF);
    unsigned short* wih = (unsigned short*)(ws + WIH_OFF);
    unsigned short* hb  = (unsigned short*)(ws + HB_OFF);
    int*       sl   = (int*)(ws + SL_OFF);
    unsigned*  bar  = (unsigned*)(ws + BAR_OFF);
    unsigned*  xcdw = (unsigned*)(ws + XCDW_OFF);

    const int tid = threadIdx.x;
    const int bid = blockIdx.x;
    const int gid = bid * NTHR + tid;        // 0..131071

    // ---------------- phase 0: convert / gather / init (verbatim R5) ----------------
    for (int i = 0; i < 16; ++i) {
        int slot = gid + i * (NGRID * NTHR);
        int row = slot >> 5;                // sentence*64 + t
        int e   = (slot & 31) << 3;
        int tok = docs[row];
        cvt8(xb + (size_t)slot * 8, embed + (size_t)tok * EMB + e);
    }
    cvt8(whh + (size_t)gid * 8,             w_hh_f + (size_t)gid * 8);
    cvt8(whh + (size_t)(gid + 131072) * 8,  w_hh_b + (size_t)gid * 8);
    {
        int dir0 = gid >> 16;
        int idx  = gid & 65535;
        cvt8(wih + (size_t)gid * 8, (dir0 ? w_ih_b : w_ih_f) + (size_t)idx * 8);
    }
    {
        s16x8 z = {0,0,0,0,0,0,0,0};
        *(s16x8*)(hb + (size_t)gid * 8) = z;   // parity-0, both dirs (made visible by grid.sync)
    }
    if (gid < NROW) {
        int c = 0;
        const int* dr = docs + gid * SEQ;
        for (int s2 = 0; s2 < SEQ; ++s2) c += (dr[s2] != 0);
        sl[gid] = c;
    }
    if (gid < 8) bar[gid] = 0u;

    // publish this WG's physical XCD id (device-scope store; race-free: slot per WG)
    if (tid == 0) {
        unsigned xcd_id;
        asm("s_getreg_b32 %0, hwreg(HW_REG_XCC_ID)" : "=s"(xcd_id));
        __hip_atomic_store(xcdw + bid, xcd_id, __ATOMIC_RELAXED, __HIP_MEMORY_SCOPE_AGENT);
    }

    cg::this_grid().sync();

    // ---------------- decode block role ----------------
    const int grp = bid & 7;         // barrier group: 32 WGs each (same dir,rg)
    const int dir = grp >> 2;        // 0 fwd, 1 bwd
    const int rg  = grp & 3;         // row group (256 rows)
    const int cgd = bid >> 3;        // 0..31 : hidden-unit chunk of 16
    const int rowbase = rg * 256;
    const int hubase  = cgd * 16;

    // Is this barrier group XCD-homogeneous? If yes, h exchange is XCD-local:
    // plain write-back stores + plain loads through the shared (coherent) L2,
    // with only a per-step L1 flash-invalidate. If not, fall back to the proven
    // device-scope write-through + acquire/L2-inv path (R5 semantics).
    bool fast;
    {
        unsigned mine = __hip_atomic_load(xcdw + bid, __ATOMIC_RELAXED, __HIP_MEMORY_SCOPE_AGENT);
        unsigned same = 1u;
        for (int j = 0; j < 32; ++j) {
            unsigned o = __hip_atomic_load(xcdw + (grp + 8 * j), __ATOMIC_RELAXED, __HIP_MEMORY_SCOPE_AGENT);
            same &= (o == mine) ? 1u : 0u;
        }
        fast = (same != 0u);
    }

    // ---------------- W -> LDS, FRAGMENT order (verbatim R5) ----------------
    {
        const unsigned short* whh_d = whh + (size_t)dir * 2048 * HID;
        const unsigned short* wih_d = wih + (size_t)dir * 2048 * EMB;
        for (int s2 = 0; s2 < 12; ++s2) {
            int S = s2 * NTHR + tid;        // 0..6143 oct-slots = [24 kc][4 g][64 lane]
            int f = S >> 6, lane_s = S & 63;
            int kc = f >> 2, g = f & 3;
            int l15s = lane_s & 15, lqs = lane_s >> 4;
            int gn = g * HID + hubase + l15s;
            int k  = kc * 32 + lqs * 8;
            const unsigned short* src = (k < HID)
                ? (whh_d + (size_t)gn * HID + k)
                : (wih_d + (size_t)gn * EMB + (k - HID));
            *(s16x8*)(Wf + (size_t)S * 8) = *(const s16x8*)src;
        }
    }
    __syncthreads();

    // ---------------- per-lane setup (verbatim R5) ----------------
    const int wid = tid >> 6, lane = tid & 63, l15 = lane & 15, lq = lane >> 4;
    const int hu = hubase + l15;
    const float* bsrc = dir ? b_b : b_f;
    const float bi_ = bsrc[hu], bf_ = bsrc[HID + hu], bg_ = bsrc[2 * HID + hu], bo_ = bsrc[3 * HID + hu];

    int rA[2];
    rA[0] = rowbase + wid * 32 + l15;
    rA[1] = rowbase + wid * 32 + 16 + l15;

    int gr8[8]; int sl8[8]; float c8[8], pool8[8];
    #pragma unroll
    for (int rf = 0; rf < 2; ++rf)
        #pragma unroll
        for (int r = 0; r < 4; ++r) {
            int k8 = rf * 4 + r;
            gr8[k8] = rowbase + wid * 32 + rf * 16 + lq * 4 + r;
            sl8[k8] = sl[gr8[k8]];
            c8[k8] = 0.f; pool8[k8] = 0.f;
        }

    // ---------------- recurrence ----------------
    #pragma unroll 1
    for (int t = 0; t < SEQ; ++t) {
        const int te = dir ? (SEQ - 1 - t) : t;
        const unsigned short* hrd = hb + (size_t)((t & 1) * 2 + dir) * NROW * HID;
        unsigned short* hwr       = hb + (size_t)((((t + 1) & 1)) * 2 + dir) * NROW * HID;

        f32x4 acc[2][4];
        #pragma unroll
        for (int rf = 0; rf < 2; ++rf)
            #pragma unroll
            for (int g = 0; g < 4; ++g)
                acc[rf][g] = (f32x4){0.f, 0.f, 0.f, 0.f};

        // A-chunk loads: plain cached loads for both h (kc<16) and x (kc>=16).
        // Fast path: freshness via same-XCD L2 + per-step L1 inv below.
        // Safe path: freshness via the acquire/L2-inv in the barrier below.
        auto ldA = [&](s16x8* dst, int kc) {
            #pragma unroll
            for (int rf = 0; rf < 2; ++rf) {
                const unsigned short* p = (kc < 16)
                    ? hrd + (size_t)rA[rf] * HID + kc * 32 + lq * 8
                    : xb + ((size_t)rA[rf] * SEQ + te) * EMB + (kc - 16) * 32 + lq * 8;
                dst[rf] = *(const s16x8*)p;
            }
        };

        s16x8 Abuf[2][2];   // [parity][rf]; prefetch distance 1 => write buf != read buf, no WAR hazard
        ldA(Abuf[0], 0);
        #pragma unroll
        for (int kc = 0; kc < 24; ++kc) {
            if (kc < 23) ldA(Abuf[(kc + 1) & 1], kc + 1);
            s16x8 Bf[4];
            #pragma unroll
            for (int g = 0; g < 4; ++g)
                Bf[g] = *(const s16x8*)(Wf + ((size_t)(kc * 4 + g) * 64 + lane) * 8);
            #pragma unroll
            for (int rf = 0; rf < 2; ++rf)
                #pragma unroll
                for (int g = 0; g < 4; ++g)
                    acc[rf][g] = __builtin_amdgcn_mfma_f32_16x16x32_bf16(
                        Abuf[kc & 1][rf], Bf[g], acc[rf][g], 0, 0, 0);
        }

        // elementwise LSTM update
        unsigned short hv8[8];
        #pragma unroll
        for (int rf = 0; rf < 2; ++rf) {
            #pragma unroll
            for (int r = 0; r < 4; ++r) {
                int k8 = rf * 4 + r;
                float iv = acc[rf][0][r] + bi_;
                float fv = acc[rf][1][r] + bf_;
                float gv = acc[rf][2][r] + bg_;
                float ov = acc[rf][3][r] + bo_;
                float cc = sigf(fv) * c8[k8] + sigf(iv) * tanh_(gv);
                c8[k8] = cc;
                float hh = sigf(ov) * tanh_(cc);
                hv8[k8] = f2bf(hh);
                if (te < sl8[k8]) pool8[k8] += hh;
            }
        }
        if (fast) {
            // plain write-back stores: land in this XCD's L2 (consumers share it)
            #pragma unroll
            for (int k8 = 0; k8 < 8; ++k8)
                hwr[(size_t)gr8[k8] * HID + hu] = hv8[k8];
        } else {
            // device-scope write-through: globally visible once vmcnt retires
            #pragma unroll
            for (int k8 = 0; k8 < 8; ++k8)
                __hip_atomic_store(hwr + (size_t)gr8[k8] * HID + hu, hv8[k8],
                                   __ATOMIC_RELAXED, __HIP_MEMORY_SCOPE_AGENT);
        }

        // 32-WG group barrier. __syncthreads drains vmcnt -> all h stores are in L2
        // (fast) / at the coherence point (safe) before tid0 bumps the counter.
        __syncthreads();
        if (tid == 0) {
            __hip_atomic_fetch_add(bar + grp, 1u, __ATOMIC_RELAXED, __HIP_MEMORY_SCOPE_AGENT);
            unsigned tgt = 32u * (unsigned)(t + 1);
            while (__hip_atomic_load(bar + grp, __ATOMIC_RELAXED, __HIP_MEMORY_SCOPE_AGENT) < tgt)
                __builtin_amdgcn_s_sleep(1);
            if (fast) {
                // L1-only flash invalidate (no sc1): this CU's L1 drops any stale h
                // lines; the shared XCD L2 (holding peers' fresh h) is untouched.
                asm volatile("buffer_inv" ::: "memory");
            } else {
                // full acquire: emits L2 invalidate so plain loads see remote h
                (void)__hip_atomic_load(bar + grp, __ATOMIC_ACQUIRE, __HIP_MEMORY_SCOPE_AGENT);
            }
        }
        __syncthreads();
    }

    // ---------------- pooled output (verbatim R5) ----------------
    #pragma unroll
    for (int k8 = 0; k8 < 8; ++k8) {
        int gr = gr8[k8];
        int b = gr >> 5, d = gr & 31;
        float denom = (float)(sl8[k8] > 0 ? sl8[k8] : 1);
        float v = (d < doc_lens[b]) ? (pool8[k8] / denom) : 0.f;
        out[(size_t)gr * 1024 + (size_t)dir * HID + hu] = v;
    }
}

extern "C" void kernel_launch(void* const* d_in, const int* in_sizes, int n_in,
                              void* d_out, int out_size, void* d_ws, size_t ws_size,
                              hipStream_t stream) {
    const int*   docs     = (const int*)d_in[0];
    const int*   doc_lens = (const int*)d_in[1];
    /* d_in[2] = max_doc_len scalar (unused; fixed 32) */
    const float* embed    = (const float*)d_in[3];
    const float* w_ih_f   = (const float*)d_in[4];
    const float* w_hh_f   = (const float*)d_in[5];
    const float* b_f      = (const float*)d_in[6];
    const float* w_ih_b   = (const float*)d_in[7];
    const float* w_hh_b   = (const float*)d_in[8];
    const float* b_b      = (const float*)d_in[9];
    float* out = (float*)d_out;
    unsigned char* wsp = (unsigned char*)d_ws;

    (void)in_sizes; (void)n_in; (void)out_size; (void)ws_size;

    hipFuncSetAttribute((const void*)lstm_enc,
                        hipFuncAttributeMaxDynamicSharedMemorySize, LDS_BYTES);

    void* args[] = { &docs, &doc_lens, &embed, &w_ih_f, &w_hh_f, &b_f,
                     &w_ih_b, &w_hh_b, &b_b, &out, &wsp };
    hipLaunchCooperativeKernel((void*)lstm_enc, dim3(NGRID), dim3(NTHR),
                               args, (unsigned)LDS_BYTES, stream);
}

// Round 8
// 1013.135 us; speedup vs baseline: 1.5461x; 1.0762x over previous
//
#include <hip/hip_runtime.h>
#include <hip/hip_bf16.h>
#include <hip/hip_cooperative_groups.h>

namespace cg = cooperative_groups;

typedef __attribute__((ext_vector_type(4))) float f32x4;
typedef __attribute__((ext_vector_type(8))) short s16x8;

// problem constants (fixed instance)
#define SEQ   64
#define EMB   256
#define HID   512
#define NROW  1024          // sentences
#define NTHR  512
#define NGRID 256
#define LDS_BYTES 98304     // 24 kc * 4 gates * 64 lanes * 16B, fragment-order W
#define BSTRIDE 32          // uints per barrier slot: one 128B line per group

// workspace layout (bytes)
#define XB_OFF   0ull                                   // bf16 x: [65536][256]
#define WHH_OFF  (XB_OFF + 65536ull * EMB * 2)          // bf16 [2][2048][512]
#define WIH_OFF  (WHH_OFF + 2ull * 2048 * HID * 2)      // bf16 [2][2048][256]
#define HB_OFF   (WIH_OFF + 2ull * 2048 * EMB * 2)      // bf16 [2 parity][2 dir][1024][512]
#define SL_OFF   (HB_OFF + 4ull * NROW * HID * 2)       // int [1024]
#define BAR_OFF  (SL_OFF + 4096ull)                     // unsigned [8*BSTRIDE]
#define XCDW_OFF (BAR_OFF + 8ull * BSTRIDE * 4ull)      // unsigned [256] : per-WG XCC id

__device__ __forceinline__ unsigned short f2bf(float f) {
    union { float f; unsigned u; } x; x.f = f;
    unsigned r = x.u + 0x7fffu + ((x.u >> 16) & 1u);   // RNE
    return (unsigned short)(r >> 16);
}
__device__ __forceinline__ void cvt8(unsigned short* dst, const float* src) {
    f32x4 v0 = *(const f32x4*)src;
    f32x4 v1 = *(const f32x4*)(src + 4);
    s16x8 o;
    o[0] = (short)f2bf(v0[0]); o[1] = (short)f2bf(v0[1]);
    o[2] = (short)f2bf(v0[2]); o[3] = (short)f2bf(v0[3]);
    o[4] = (short)f2bf(v1[0]); o[5] = (short)f2bf(v1[1]);
    o[6] = (short)f2bf(v1[2]); o[7] = (short)f2bf(v1[3]);
    *(s16x8*)dst = o;
}
__device__ __forceinline__ float sigf(float x)  { return 1.0f / (1.0f + __expf(-x)); }
__device__ __forceinline__ float tanh_(float x) { return 2.0f / (1.0f + __expf(-2.0f * x)) - 1.0f; }

__global__ void __launch_bounds__(NTHR, 2)
lstm_enc(const int* __restrict__ docs, const int* __restrict__ doc_lens,
         const float* __restrict__ embed,
         const float* __restrict__ w_ih_f, const float* __restrict__ w_hh_f, const float* __restrict__ b_f,
         const float* __restrict__ w_ih_b, const float* __restrict__ w_hh_b, const float* __restrict__ b_b,
         float* __restrict__ out, unsigned char* __restrict__ ws)
{
    extern __shared__ unsigned short Wf[];   // [24 kc][4 g][64 lane][8] bf16, MFMA B-frag order

    unsigned short* xb  = (unsigned short*)(ws + XB_OFF);
    unsigned short* whh = (unsigned short*)(ws + WHH_OFF);
    unsigned short* wih = (unsigned short*)(ws + WIH_OFF);
    unsigned short* hb  = (unsigned short*)(ws + HB_OFF);
    int*       sl   = (int*)(ws + SL_OFF);
    unsigned*  bar  = (unsigned*)(ws + BAR_OFF);
    unsigned*  xcdw = (unsigned*)(ws + XCDW_OFF);

    const int tid = threadIdx.x;
    const int bid = blockIdx.x;
    const int gid = bid * NTHR + tid;        // 0..131071

    // ---------------- phase 0: convert / gather / init (verbatim R7) ----------------
    for (int i = 0; i < 16; ++i) {
        int slot = gid + i * (NGRID * NTHR);
        int row = slot >> 5;                // sentence*64 + t
        int e   = (slot & 31) << 3;
        int tok = docs[row];
        cvt8(xb + (size_t)slot * 8, embed + (size_t)tok * EMB + e);
    }
    cvt8(whh + (size_t)gid * 8,             w_hh_f + (size_t)gid * 8);
    cvt8(whh + (size_t)(gid + 131072) * 8,  w_hh_b + (size_t)gid * 8);
    {
        int dir0 = gid >> 16;
        int idx  = gid & 65535;
        cvt8(wih + (size_t)gid * 8, (dir0 ? w_ih_b : w_ih_f) + (size_t)idx * 8);
    }
    {
        s16x8 z = {0,0,0,0,0,0,0,0};
        *(s16x8*)(hb + (size_t)gid * 8) = z;   // parity-0, both dirs (made visible by grid.sync)
    }
    if (gid < NROW) {
        int c = 0;
        const int* dr = docs + gid * SEQ;
        for (int s2 = 0; s2 < SEQ; ++s2) c += (dr[s2] != 0);
        sl[gid] = c;
    }
    if (gid < 8 * BSTRIDE) bar[gid] = 0u;

    // publish this WG's physical XCD id
    if (tid == 0) {
        unsigned xcd_id;
        asm("s_getreg_b32 %0, hwreg(HW_REG_XCC_ID)" : "=s"(xcd_id));
        __hip_atomic_store(xcdw + bid, xcd_id, __ATOMIC_RELAXED, __HIP_MEMORY_SCOPE_AGENT);
    }

    cg::this_grid().sync();

    // ---------------- decode block role ----------------
    const int grp = bid & 7;         // barrier group: 32 WGs each (same dir,rg)
    const int dir = grp >> 2;        // 0 fwd, 1 bwd
    const int rg  = grp & 3;         // row group (256 rows)
    const int cgd = bid >> 3;        // 0..31 : hidden-unit chunk of 16
    const int rowbase = rg * 256;
    const int hubase  = cgd * 16;
    unsigned* mybar = bar + grp * BSTRIDE;

    // XCD-homogeneity check -> fast (XCD-local L2 exchange) or safe (R5 semantics)
    bool fast;
    {
        unsigned mine = __hip_atomic_load(xcdw + bid, __ATOMIC_RELAXED, __HIP_MEMORY_SCOPE_AGENT);
        unsigned same = 1u;
        for (int j = 0; j < 32; ++j) {
            unsigned o = __hip_atomic_load(xcdw + (grp + 8 * j), __ATOMIC_RELAXED, __HIP_MEMORY_SCOPE_AGENT);
            same &= (o == mine) ? 1u : 0u;
        }
        fast = (same != 0u);
    }

    // ---------------- W -> LDS, FRAGMENT order (verbatim R7) ----------------
    {
        const unsigned short* whh_d = whh + (size_t)dir * 2048 * HID;
        const unsigned short* wih_d = wih + (size_t)dir * 2048 * EMB;
        for (int s2 = 0; s2 < 12; ++s2) {
            int S = s2 * NTHR + tid;        // 0..6143 oct-slots = [24 kc][4 g][64 lane]
            int f = S >> 6, lane_s = S & 63;
            int kc = f >> 2, g = f & 3;
            int l15s = lane_s & 15, lqs = lane_s >> 4;
            int gn = g * HID + hubase + l15s;
            int k  = kc * 32 + lqs * 8;
            const unsigned short* src = (k < HID)
                ? (whh_d + (size_t)gn * HID + k)
                : (wih_d + (size_t)gn * EMB + (k - HID));
            *(s16x8*)(Wf + (size_t)S * 8) = *(const s16x8*)src;
        }
    }
    __syncthreads();

    // ---------------- per-lane setup ----------------
    const int wid = tid >> 6, lane = tid & 63, l15 = lane & 15, lq = lane >> 4;
    const int hu = hubase + l15;
    const float* bsrc = dir ? b_b : b_f;
    float bg4[4];
    #pragma unroll
    for (int g = 0; g < 4; ++g) bg4[g] = bsrc[g * HID + hu];

    int rA[2];
    rA[0] = rowbase + wid * 32 + l15;
    rA[1] = rowbase + wid * 32 + 16 + l15;

    int gr8[8]; int sl8[8]; float c8[8], pool8[8];
    #pragma unroll
    for (int rf = 0; rf < 2; ++rf)
        #pragma unroll
        for (int r = 0; r < 4; ++r) {
            int k8 = rf * 4 + r;
            gr8[k8] = rowbase + wid * 32 + rf * 16 + lq * 4 + r;
            sl8[k8] = sl[gr8[k8]];
            c8[k8] = 0.f; pool8[k8] = 0.f;
        }

    f32x4 acc[2][4];

    auto ldB = [&](s16x8* dst, int kc) {
        #pragma unroll
        for (int g = 0; g < 4; ++g)
            dst[g] = *(const s16x8*)(Wf + ((size_t)(kc * 4 + g) * 64 + lane) * 8);
    };
    auto ldX = [&](s16x8* dst, int kc, int te2) {
        #pragma unroll
        for (int rf = 0; rf < 2; ++rf)
            dst[rf] = *(const s16x8*)(xb + ((size_t)rA[rf] * SEQ + te2) * EMB + (kc - 16) * 32 + lq * 8);
    };
    auto ldH = [&](s16x8* dst, int kc, const unsigned short* hsrc) {
        #pragma unroll
        for (int rf = 0; rf < 2; ++rf)
            dst[rf] = *(const s16x8*)(hsrc + (size_t)rA[rf] * HID + kc * 32 + lq * 8);
    };
    // x-part: acc = bias + x_te * W_ih (kc 16..23). Independent of h — runs pre-barrier.
    auto xpart = [&](int te2) {
        #pragma unroll
        for (int rf = 0; rf < 2; ++rf)
            #pragma unroll
            for (int g = 0; g < 4; ++g)
                acc[rf][g] = (f32x4){bg4[g], bg4[g], bg4[g], bg4[g]};
        s16x8 Ax[3][2];
        ldX(Ax[0], 16, te2);
        ldX(Ax[1], 17, te2);
        #pragma unroll
        for (int i = 0; i < 8; ++i) {
            if (i + 2 < 8) ldX(Ax[(i + 2) % 3], 18 + i, te2);   // distance-2, 3-buffer: no WAR
            s16x8 Bf[4]; ldB(Bf, 16 + i);
            #pragma unroll
            for (int rf = 0; rf < 2; ++rf)
                #pragma unroll
                for (int g = 0; g < 4; ++g)
                    acc[rf][g] = __builtin_amdgcn_mfma_f32_16x16x32_bf16(
                        Ax[i % 3][rf], Bf[g], acc[rf][g], 0, 0, 0);
        }
    };

    // prologue: x-part of step 0
    xpart(dir ? (SEQ - 1) : 0);

    // ---------------- recurrence (split-phase) ----------------
    #pragma unroll 1
    for (int t = 0; t < SEQ; ++t) {
        const int te = dir ? (SEQ - 1 - t) : t;
        const unsigned short* hrd = hb + (size_t)((t & 1) * 2 + dir) * NROW * HID;
        unsigned short* hwr       = hb + (size_t)((((t + 1) & 1)) * 2 + dir) * NROW * HID;

        // ---- wait for epoch t: all 32 WGs' h_t stores visible (t=0 trivial) ----
        __syncthreads();
        if (tid == 0) {
            unsigned tgt = 32u * (unsigned)t;
            while (__hip_atomic_load(mybar, __ATOMIC_RELAXED, __HIP_MEMORY_SCOPE_AGENT) < tgt)
                __builtin_amdgcn_s_sleep(1);
            if (fast) {
                asm volatile("buffer_inv" ::: "memory");   // L1-only; XCD L2 holds fresh h
            } else {
                (void)__hip_atomic_load(mybar, __ATOMIC_ACQUIRE, __HIP_MEMORY_SCOPE_AGENT);
            }
        }
        __syncthreads();

        // ---- h-part: acc += h_t * W_hh (kc 0..15) ----
        {
            s16x8 Ah[3][2];
            ldH(Ah[0], 0, hrd);
            ldH(Ah[1], 1, hrd);
            #pragma unroll
            for (int i = 0; i < 16; ++i) {
                if (i + 2 < 16) ldH(Ah[(i + 2) % 3], i + 2, hrd);
                s16x8 Bf[4]; ldB(Bf, i);
                #pragma unroll
                for (int rf = 0; rf < 2; ++rf)
                    #pragma unroll
                    for (int g = 0; g < 4; ++g)
                        acc[rf][g] = __builtin_amdgcn_mfma_f32_16x16x32_bf16(
                            Ah[i % 3][rf], Bf[g], acc[rf][g], 0, 0, 0);
            }
        }

        // ---- elementwise LSTM update + h_{t+1} store ----
        unsigned short hv8[8];
        #pragma unroll
        for (int rf = 0; rf < 2; ++rf) {
            #pragma unroll
            for (int r = 0; r < 4; ++r) {
                int k8 = rf * 4 + r;
                float iv = acc[rf][0][r];
                float fv = acc[rf][1][r];
                float gv = acc[rf][2][r];
                float ov = acc[rf][3][r];
                float cc = sigf(fv) * c8[k8] + sigf(iv) * tanh_(gv);
                c8[k8] = cc;
                float hh = sigf(ov) * tanh_(cc);
                hv8[k8] = f2bf(hh);
                if (te < sl8[k8]) pool8[k8] += hh;
            }
        }
        if (fast) {
            #pragma unroll
            for (int k8 = 0; k8 < 8; ++k8)
                hwr[(size_t)gr8[k8] * HID + hu] = hv8[k8];
        } else {
            #pragma unroll
            for (int k8 = 0; k8 < 8; ++k8)
                __hip_atomic_store(hwr + (size_t)gr8[k8] * HID + hu, hv8[k8],
                                   __ATOMIC_RELAXED, __HIP_MEMORY_SCOPE_AGENT);
        }

        // ---- signal epoch t+1 (all waves drain stores at the s_barrier first) ----
        __syncthreads();
        if (t < SEQ - 1) {
            if (tid == 0)
                __hip_atomic_fetch_add(mybar, 1u, __ATOMIC_RELAXED, __HIP_MEMORY_SCOPE_AGENT);
            // ---- x-part for t+1: overlaps peers' arrival + gather latency ----
            xpart(dir ? (SEQ - 2 - t) : (t + 1));
        }
    }

    // ---------------- pooled output (verbatim R7) ----------------
    #pragma unroll
    for (int k8 = 0; k8 < 8; ++k8) {
        int gr = gr8[k8];
        int b = gr >> 5, d = gr & 31;
        float denom = (float)(sl8[k8] > 0 ? sl8[k8] : 1);
        float v = (d < doc_lens[b]) ? (pool8[k8] / denom) : 0.f;
        out[(size_t)gr * 1024 + (size_t)dir * HID + hu] = v;
    }
}

extern "C" void kernel_launch(void* const* d_in, const int* in_sizes, int n_in,
                              void* d_out, int out_size, void* d_ws, size_t ws_size,
                              hipStream_t stream) {
    const int*   docs     = (const int*)d_in[0];
    const int*   doc_lens = (const int*)d_in[1];
    /* d_in[2] = max_doc_len scalar (unused; fixed 32) */
    const float* embed    = (const float*)d_in[3];
    const float* w_ih_f   = (const float*)d_in[4];
    const float* w_hh_f   = (const float*)d_in[5];
    const float* b_f      = (const float*)d_in[6];
    const float* w_ih_b   = (const float*)d_in[7];
    const float* w_hh_b   = (const float*)d_in[8];
    const float* b_b      = (const float*)d_in[9];
    float* out = (float*)d_out;
    unsigned char* wsp = (unsigned char*)d_ws;

    (void)in_sizes; (void)n_in; (void)out_size; (void)ws_size;

    hipFuncSetAttribute((const void*)lstm_enc,
                        hipFuncAttributeMaxDynamicSharedMemorySize, LDS_BYTES);

    void* args[] = { &docs, &doc_lens, &embed, &w_ih_f, &w_hh_f, &b_f,
                     &w_ih_b, &w_hh_b, &b_b, &out, &wsp };
    hipLaunchCooperativeKernel((void*)lstm_enc, dim3(NGRID), dim3(NTHR),
                               args, (unsigned)LDS_BYTES, stream);
}

// Round 9
// 965.942 us; speedup vs baseline: 1.6217x; 1.0489x over previous
//
#include <hip/hip_runtime.h>
#include <hip/hip_bf16.h>
#include <hip/hip_cooperative_groups.h>

namespace cg = cooperative_groups;

typedef __attribute__((ext_vector_type(4))) float f32x4;
typedef __attribute__((ext_vector_type(8))) short s16x8;

// problem constants (fixed instance)
#define SEQ   64
#define EMB   256
#define HID   512
#define NROW  1024          // sentences
#define NTHR  512
#define NGRID 256
#define LDS_BYTES 98304     // 24 kc * 4 gates * 64 lanes * 16B, fragment-order W
#define BSTRIDE 32          // uints per group flag line: 32 flags * 4B = one 128B line

// workspace layout (bytes)
#define XB_OFF   0ull                                   // bf16 x: [65536][256]
#define WHH_OFF  (XB_OFF + 65536ull * EMB * 2)          // bf16 [2][2048][512]
#define WIH_OFF  (WHH_OFF + 2ull * 2048 * HID * 2)      // bf16 [2][2048][256]
#define HB_OFF   (WIH_OFF + 2ull * 2048 * EMB * 2)      // bf16 [2 parity][2 dir][1024][512]
#define SL_OFF   (HB_OFF + 4ull * NROW * HID * 2)       // int [1024]
#define BAR_OFF  (SL_OFF + 4096ull)                     // unsigned flag[8 grp][32 wg] (128B/grp)
#define XCDW_OFF (BAR_OFF + 8ull * BSTRIDE * 4ull)      // unsigned [256] : per-WG XCC id

__device__ __forceinline__ unsigned short f2bf(float f) {
    union { float f; unsigned u; } x; x.f = f;
    unsigned r = x.u + 0x7fffu + ((x.u >> 16) & 1u);   // RNE
    return (unsigned short)(r >> 16);
}
__device__ __forceinline__ void cvt8(unsigned short* dst, const float* src) {
    f32x4 v0 = *(const f32x4*)src;
    f32x4 v1 = *(const f32x4*)(src + 4);
    s16x8 o;
    o[0] = (short)f2bf(v0[0]); o[1] = (short)f2bf(v0[1]);
    o[2] = (short)f2bf(v0[2]); o[3] = (short)f2bf(v0[3]);
    o[4] = (short)f2bf(v1[0]); o[5] = (short)f2bf(v1[1]);
    o[6] = (short)f2bf(v1[2]); o[7] = (short)f2bf(v1[3]);
    *(s16x8*)dst = o;
}
__device__ __forceinline__ float sigf(float x)  { return 1.0f / (1.0f + __expf(-x)); }
__device__ __forceinline__ float tanh_(float x) { return 2.0f / (1.0f + __expf(-2.0f * x)) - 1.0f; }

// L2-hit load that bypasses L1 (sc0): used for flag polling on the fast path.
__device__ __forceinline__ unsigned ld_flag_sc0(const unsigned* p) {
    unsigned v;
    asm volatile("global_load_dword %0, %1, off sc0\n\t"
                 "s_waitcnt vmcnt(0)"
                 : "=v"(v) : "v"(p) : "memory");
    return v;
}

__global__ void __launch_bounds__(NTHR, 2)
lstm_enc(const int* __restrict__ docs, const int* __restrict__ doc_lens,
         const float* __restrict__ embed,
         const float* __restrict__ w_ih_f, const float* __restrict__ w_hh_f, const float* __restrict__ b_f,
         const float* __restrict__ w_ih_b, const float* __restrict__ w_hh_b, const float* __restrict__ b_b,
         float* __restrict__ out, unsigned char* __restrict__ ws)
{
    extern __shared__ unsigned short Wf[];   // [24 kc][4 g][64 lane][8] bf16, MFMA B-frag order

    unsigned short* xb  = (unsigned short*)(ws + XB_OFF);
    unsigned short* whh = (unsigned short*)(ws + WHH_OFF);
    unsigned short* wih = (unsigned short*)(ws + WIH_OFF);
    unsigned short* hb  = (unsigned short*)(ws + HB_OFF);
    int*       sl   = (int*)(ws + SL_OFF);
    unsigned*  bar  = (unsigned*)(ws + BAR_OFF);
    unsigned*  xcdw = (unsigned*)(ws + XCDW_OFF);

    const int tid = threadIdx.x;
    const int bid = blockIdx.x;
    const int gid = bid * NTHR + tid;        // 0..131071

    // ---------------- phase 0: convert / gather / init (verbatim R8) ----------------
    for (int i = 0; i < 16; ++i) {
        int slot = gid + i * (NGRID * NTHR);
        int row = slot >> 5;                // sentence*64 + t
        int e   = (slot & 31) << 3;
        int tok = docs[row];
        cvt8(xb + (size_t)slot * 8, embed + (size_t)tok * EMB + e);
    }
    cvt8(whh + (size_t)gid * 8,             w_hh_f + (size_t)gid * 8);
    cvt8(whh + (size_t)(gid + 131072) * 8,  w_hh_b + (size_t)gid * 8);
    {
        int dir0 = gid >> 16;
        int idx  = gid & 65535;
        cvt8(wih + (size_t)gid * 8, (dir0 ? w_ih_b : w_ih_f) + (size_t)idx * 8);
    }
    {
        s16x8 z = {0,0,0,0,0,0,0,0};
        *(s16x8*)(hb + (size_t)gid * 8) = z;   // parity-0, both dirs (made visible by grid.sync)
    }
    if (gid < NROW) {
        int c = 0;
        const int* dr = docs + gid * SEQ;
        for (int s2 = 0; s2 < SEQ; ++s2) c += (dr[s2] != 0);
        sl[gid] = c;
    }
    if (gid < 8 * BSTRIDE) bar[gid] = 0u;      // all flags = epoch 0

    // publish this WG's physical XCD id
    if (tid == 0) {
        unsigned xcd_id;
        asm("s_getreg_b32 %0, hwreg(HW_REG_XCC_ID)" : "=s"(xcd_id));
        __hip_atomic_store(xcdw + bid, xcd_id, __ATOMIC_RELAXED, __HIP_MEMORY_SCOPE_AGENT);
    }

    cg::this_grid().sync();

    // ---------------- decode block role ----------------
    const int grp = bid & 7;         // barrier group: 32 WGs each (same dir,rg)
    const int dir = grp >> 2;        // 0 fwd, 1 bwd
    const int rg  = grp & 3;         // row group (256 rows)
    const int cgd = bid >> 3;        // 0..31 : hidden-unit chunk of 16
    const int rowbase = rg * 256;
    const int hubase  = cgd * 16;
    unsigned* gflags  = bar + grp * BSTRIDE;   // this group's 32 flags (one line)
    unsigned* myflag  = gflags + cgd;

    // XCD-homogeneity check -> fast (XCD-local L2 exchange) or safe (R5 semantics)
    bool fast;
    {
        unsigned mine = __hip_atomic_load(xcdw + bid, __ATOMIC_RELAXED, __HIP_MEMORY_SCOPE_AGENT);
        unsigned same = 1u;
        for (int j = 0; j < 32; ++j) {
            unsigned o = __hip_atomic_load(xcdw + (grp + 8 * j), __ATOMIC_RELAXED, __HIP_MEMORY_SCOPE_AGENT);
            same &= (o == mine) ? 1u : 0u;
        }
        fast = (same != 0u);
    }

    // ---------------- W -> LDS, FRAGMENT order (verbatim R8) ----------------
    {
        const unsigned short* whh_d = whh + (size_t)dir * 2048 * HID;
        const unsigned short* wih_d = wih + (size_t)dir * 2048 * EMB;
        for (int s2 = 0; s2 < 12; ++s2) {
            int S = s2 * NTHR + tid;        // 0..6143 oct-slots = [24 kc][4 g][64 lane]
            int f = S >> 6, lane_s = S & 63;
            int kc = f >> 2, g = f & 3;
            int l15s = lane_s & 15, lqs = lane_s >> 4;
            int gn = g * HID + hubase + l15s;
            int k  = kc * 32 + lqs * 8;
            const unsigned short* src = (k < HID)
                ? (whh_d + (size_t)gn * HID + k)
                : (wih_d + (size_t)gn * EMB + (k - HID));
            *(s16x8*)(Wf + (size_t)S * 8) = *(const s16x8*)src;
        }
    }
    __syncthreads();

    // ---------------- per-lane setup ----------------
    const int wid = tid >> 6, lane = tid & 63, l15 = lane & 15, lq = lane >> 4;
    const int hu = hubase + l15;
    const float* bsrc = dir ? b_b : b_f;
    float bg4[4];
    #pragma unroll
    for (int g = 0; g < 4; ++g) bg4[g] = bsrc[g * HID + hu];

    int rA[2];
    rA[0] = rowbase + wid * 32 + l15;
    rA[1] = rowbase + wid * 32 + 16 + l15;

    int gr8[8]; int sl8[8]; float c8[8], pool8[8];
    #pragma unroll
    for (int rf = 0; rf < 2; ++rf)
        #pragma unroll
        for (int r = 0; r < 4; ++r) {
            int k8 = rf * 4 + r;
            gr8[k8] = rowbase + wid * 32 + rf * 16 + lq * 4 + r;
            sl8[k8] = sl[gr8[k8]];
            c8[k8] = 0.f; pool8[k8] = 0.f;
        }

    f32x4 acc[2][4];

    auto ldB = [&](s16x8* dst, int kc) {
        #pragma unroll
        for (int g = 0; g < 4; ++g)
            dst[g] = *(const s16x8*)(Wf + ((size_t)(kc * 4 + g) * 64 + lane) * 8);
    };
    auto ldX = [&](s16x8* dst, int kc, int te2) {
        #pragma unroll
        for (int rf = 0; rf < 2; ++rf)
            dst[rf] = *(const s16x8*)(xb + ((size_t)rA[rf] * SEQ + te2) * EMB + (kc - 16) * 32 + lq * 8);
    };
    auto ldH = [&](s16x8* dst, int kc, const unsigned short* hsrc) {
        #pragma unroll
        for (int rf = 0; rf < 2; ++rf)
            dst[rf] = *(const s16x8*)(hsrc + (size_t)rA[rf] * HID + kc * 32 + lq * 8);
    };
    // x-part: acc = bias + x_te * W_ih (kc 16..23). Independent of h — runs post-signal.
    auto xpart = [&](int te2) {
        #pragma unroll
        for (int rf = 0; rf < 2; ++rf)
            #pragma unroll
            for (int g = 0; g < 4; ++g)
                acc[rf][g] = (f32x4){bg4[g], bg4[g], bg4[g], bg4[g]};
        s16x8 Ax[3][2];
        ldX(Ax[0], 16, te2);
        ldX(Ax[1], 17, te2);
        #pragma unroll
        for (int i = 0; i < 8; ++i) {
            if (i + 2 < 8) ldX(Ax[(i + 2) % 3], 18 + i, te2);   // distance-2, 3-buffer: no WAR
            s16x8 Bf[4]; ldB(Bf, 16 + i);
            #pragma unroll
            for (int rf = 0; rf < 2; ++rf)
                #pragma unroll
                for (int g = 0; g < 4; ++g)
                    acc[rf][g] = __builtin_amdgcn_mfma_f32_16x16x32_bf16(
                        Ax[i % 3][rf], Bf[g], acc[rf][g], 0, 0, 0);
        }
    };

    // prologue: x-part of step 0
    xpart(dir ? (SEQ - 1) : 0);

    // ---------------- recurrence (split-phase, flag barrier) ----------------
    #pragma unroll 1
    for (int t = 0; t < SEQ; ++t) {
        const int te = dir ? (SEQ - 1 - t) : t;
        const unsigned short* hrd = hb + (size_t)((t & 1) * 2 + dir) * NROW * HID;
        unsigned short* hwr       = hb + (size_t)((((t + 1) & 1)) * 2 + dir) * NROW * HID;

        // ---- wait for epoch t: lane-parallel poll of the group's 32 flags ----
        // wave 0 polls (lanes 0..31, one flag each); other waves park at the barrier.
        if (tid < 64) {
            const unsigned tgt = (unsigned)t;
            const bool act = (lane < 32);
            const unsigned* fp = gflags + (lane & 31);
            if (fast) {
                while (__ballot(act && (ld_flag_sc0(fp) < tgt)) != 0ull) {}
                // L1-only flash invalidate: drop stale h lines; XCD L2 (fresh h) intact.
                asm volatile("buffer_inv" ::: "memory");
            } else {
                while (__ballot(act && (__hip_atomic_load(fp, __ATOMIC_RELAXED,
                                        __HIP_MEMORY_SCOPE_AGENT) < tgt)) != 0ull) {}
                // full acquire: L2 invalidate so plain loads see remote h
                (void)__hip_atomic_load(gflags, __ATOMIC_ACQUIRE, __HIP_MEMORY_SCOPE_AGENT);
            }
        }
        __syncthreads();

        // ---- h-part: acc += h_t * W_hh (kc 0..15), distance-3 prefetch ----
        {
            s16x8 Ah[4][2];
            ldH(Ah[0], 0, hrd);
            ldH(Ah[1], 1, hrd);
            ldH(Ah[2], 2, hrd);
            #pragma unroll
            for (int i = 0; i < 16; ++i) {
                if (i + 3 < 16) ldH(Ah[(i + 3) & 3], i + 3, hrd);
                s16x8 Bf[4]; ldB(Bf, i);
                #pragma unroll
                for (int rf = 0; rf < 2; ++rf)
                    #pragma unroll
                    for (int g = 0; g < 4; ++g)
                        acc[rf][g] = __builtin_amdgcn_mfma_f32_16x16x32_bf16(
                            Ah[i & 3][rf], Bf[g], acc[rf][g], 0, 0, 0);
            }
        }

        // ---- elementwise LSTM update + h_{t+1} store ----
        unsigned short hv8[8];
        #pragma unroll
        for (int rf = 0; rf < 2; ++rf) {
            #pragma unroll
            for (int r = 0; r < 4; ++r) {
                int k8 = rf * 4 + r;
                float iv = acc[rf][0][r];
                float fv = acc[rf][1][r];
                float gv = acc[rf][2][r];
                float ov = acc[rf][3][r];
                float cc = sigf(fv) * c8[k8] + sigf(iv) * tanh_(gv);
                c8[k8] = cc;
                float hh = sigf(ov) * tanh_(cc);
                hv8[k8] = f2bf(hh);
                if (te < sl8[k8]) pool8[k8] += hh;
            }
        }
        if (fast) {
            // plain write-back stores: L1 is write-through, lands in XCD-shared L2
            #pragma unroll
            for (int k8 = 0; k8 < 8; ++k8)
                hwr[(size_t)gr8[k8] * HID + hu] = hv8[k8];
        } else {
            // device-scope write-through: at coherence point once vmcnt retires
            #pragma unroll
            for (int k8 = 0; k8 < 8; ++k8)
                __hip_atomic_store(hwr + (size_t)gr8[k8] * HID + hu, hv8[k8],
                                   __ATOMIC_RELAXED, __HIP_MEMORY_SCOPE_AGENT);
        }

        // ---- signal epoch t+1: one plain (fast) / agent (safe) flag store ----
        // __syncthreads drains every wave's vmcnt -> all h stores are in L2 (fast)
        // or at the coherence point (safe) before the flag is bumped.
        __syncthreads();
        if (t < SEQ - 1) {
            if (tid == 0) {
                if (fast)
                    __hip_atomic_store(myflag, (unsigned)(t + 1),
                                       __ATOMIC_RELAXED, __HIP_MEMORY_SCOPE_WORKGROUP);
                else
                    __hip_atomic_store(myflag, (unsigned)(t + 1),
                                       __ATOMIC_RELAXED, __HIP_MEMORY_SCOPE_AGENT);
            }
            // ---- x-part for t+1: overlaps peers' arrival + gather latency ----
            xpart(dir ? (SEQ - 2 - t) : (t + 1));
        }
    }

    // ---------------- pooled output (verbatim R8) ----------------
    #pragma unroll
    for (int k8 = 0; k8 < 8; ++k8) {
        int gr = gr8[k8];
        int b = gr >> 5, d = gr & 31;
        float denom = (float)(sl8[k8] > 0 ? sl8[k8] : 1);
        float v = (d < doc_lens[b]) ? (pool8[k8] / denom) : 0.f;
        out[(size_t)gr * 1024 + (size_t)dir * HID + hu] = v;
    }
}

extern "C" void kernel_launch(void* const* d_in, const int* in_sizes, int n_in,
                              void* d_out, int out_size, void* d_ws, size_t ws_size,
                              hipStream_t stream) {
    const int*   docs     = (const int*)d_in[0];
    const int*   doc_lens = (const int*)d_in[1];
    /* d_in[2] = max_doc_len scalar (unused; fixed 32) */
    const float* embed    = (const float*)d_in[3];
    const float* w_ih_f   = (const float*)d_in[4];
    const float* w_hh_f   = (const float*)d_in[5];
    const float* b_f      = (const float*)d_in[6];
    const float* w_ih_b   = (const float*)d_in[7];
    const float* w_hh_b   = (const float*)d_in[8];
    const float* b_b      = (const float*)d_in[9];
    float* out = (float*)d_out;
    unsigned char* wsp = (unsigned char*)d_ws;

    (void)in_sizes; (void)n_in; (void)out_size; (void)ws_size;

    hipFuncSetAttribute((const void*)lstm_enc,
                        hipFuncAttributeMaxDynamicSharedMemorySize, LDS_BYTES);

    void* args[] = { &docs, &doc_lens, &embed, &w_ih_f, &w_hh_f, &b_f,
                     &w_ih_b, &w_hh_b, &b_b, &out, &wsp };
    hipLaunchCooperativeKernel((void*)lstm_enc, dim3(NGRID), dim3(NTHR),
                               args, (unsigned)LDS_BYTES, stream);
}